// Round 3
// baseline (141.034 us; speedup 1.0000x reference)
//
#include <hip/hip_runtime.h>
#include <hip/hip_bf16.h>

// Problem constants (fixed by the reference).
#define N_NODES 10000
#define DEG     32
#define CH      16
#define IN_DIM  4
#define BATCH   8
#define E_EDGES (N_NODES * DEG)        // 320000
#define WI_STRIDE (E_EDGES * CH)       // 5,120,000 floats between w[i] planes
#define P_COUNT 625                    // 512*625 == E_EDGES : gather period in n
#define LX_STRIDE 36                   // 32 floats/row + 4 pad (16B-aligned, 2-phase reads)

// Kernel 1: transpose/pad x[B][N][4] -> xt[N+1][B][4] (node-major, 128 B/node).
__global__ __launch_bounds__(256) void lcg_transpose(const float* __restrict__ x,
                                                     float* __restrict__ xt) {
    int t = blockIdx.x * 256 + threadIdx.x;
    if (t < BATCH * N_NODES) {
        int b = t / N_NODES;
        int node = t - b * N_NODES;
        float4 v = *(const float4*)(x + 4 * t);          // x[b][node][0..3]
        *(float4*)(xt + node * 32 + b * 4) = v;
    } else if (t < BATCH * N_NODES + 8) {
        int r = t - BATCH * N_NODES;                     // zero pad row N_NODES
        *(float4*)(xt + N_NODES * 32 + r * 4) = make_float4(0.f, 0.f, 0.f, 0.f);
    }
}

// Kernel 2: one block per p (0..624). Gather index k = (512n+16d+c) mod 320000;
// n = p+625j all share k = 512p + s with s = 16d+c in [0,512) -> edges[512p..512p+512).
// Stage A: gather 512 node-rows (128 B each, full-line) into LDS.
// Stage B: thread (j,c) accumulates all 8 batches; weight loads are full 64 B
// lines per j-cluster, each weight read exactly once (nontemporal, single-use).
__global__ __launch_bounds__(256, 2) void lcg_main(
    const float* __restrict__ xt,     // [N+1][32]
    const int*   __restrict__ edges,  // [E]
    const float* __restrict__ w,      // [4][E][16]
    float*       __restrict__ out)    // [8][N][16]
{
    __shared__ float lx[512 * LX_STRIDE];   // 73728 B -> 2 blocks/CU

    int p = blockIdx.x;
    int t = threadIdx.x;

    // ---- Stage A: edges + gather into LDS ----
    {
        int sub = t & 7;              // which float4 of the 128 B node row
        int rg  = t >> 3;             // 0..31 ; rows s = rg + 32k
        const int* ep = edges + 512 * p;
        int nd[16];
#pragma unroll
        for (int k = 0; k < 16; k++) nd[k] = ep[rg + 32 * k];
#pragma unroll
        for (int k = 0; k < 16; k++) {
            int s = rg + 32 * k;
            float4 v = *(const float4*)(xt + nd[k] * 32 + sub * 4);
            *(float4*)(&lx[s * LX_STRIDE + sub * 4]) = v;
        }
    }
    __syncthreads();

    // ---- Stage B: compute ----
    int c = t & 15;                   // lanes: 16 c consecutive -> 64 B w-lines
    int j = t >> 4;                   // 0..15
    int n = p + P_COUNT * j;

    const float* wp = w + (n * DEG) * CH + c;   // w[0][32n][c]
    float acc[BATCH];
#pragma unroll
    for (int b = 0; b < BATCH; b++) acc[b] = 0.0f;

#pragma unroll 2
    for (int d = 0; d < DEG; d++) {
        float w0 = __builtin_nontemporal_load(wp + d * CH);
        float w1 = __builtin_nontemporal_load(wp + d * CH + WI_STRIDE);
        float w2 = __builtin_nontemporal_load(wp + d * CH + 2 * WI_STRIDE);
        float w3 = __builtin_nontemporal_load(wp + d * CH + 3 * WI_STRIDE);
        const float* lp = &lx[(16 * d + c) * LX_STRIDE];
        float4 xv[BATCH];
#pragma unroll
        for (int b = 0; b < BATCH; b++) xv[b] = *(const float4*)(lp + 4 * b);
#pragma unroll
        for (int b = 0; b < BATCH; b++)
            acc[b] += xv[b].x * w0 + xv[b].y * w1 + xv[b].z * w2 + xv[b].w * w3;
    }

    int ob = n * CH + c;
#pragma unroll
    for (int b = 0; b < BATCH; b++)
        __builtin_nontemporal_store(acc[b], out + b * (N_NODES * CH) + ob);
}

extern "C" void kernel_launch(void* const* d_in, const int* in_sizes, int n_in,
                              void* d_out, int out_size, void* d_ws, size_t ws_size,
                              hipStream_t stream) {
    const float* x     = (const float*)d_in[0];   // [8][10000][4] f32
    const int*   edges = (const int*)d_in[1];     // [320000] int
    const float* w     = (const float*)d_in[2];   // [4][320000][16] f32
    float* out = (float*)d_out;                   // [8][10000][16] f32
    float* xt  = (float*)d_ws;                    // (10001*32) f32 = 1.28 MB

    int tr_total  = BATCH * N_NODES + 8;                  // 80008
    int tr_blocks = (tr_total + 255) / 256;               // 313
    lcg_transpose<<<tr_blocks, 256, 0, stream>>>(x, xt);

    lcg_main<<<P_COUNT, 256, 0, stream>>>(xt, edges, w, out);
}